// Round 16
// baseline (480.589 us; speedup 1.0000x reference)
//
#include <hip/hip_runtime.h>
#include <hip/hip_bf16.h>

typedef __bf16 bf16_t;
typedef __bf16 bf16x8 __attribute__((ext_vector_type(8)));
typedef float  f32x4  __attribute__((ext_vector_type(4)));
typedef int    i32x4  __attribute__((ext_vector_type(4)));
typedef signed char i8x16 __attribute__((ext_vector_type(16)));

#define M_DIM 4096
#define N_DIM 12288
#define K_DIM 3072
#define NBLK  96      // K_DIM / 32 quant blocks per output row

#define BM 256
#define BN 256
#define BKB 128               // K-bytes (=elems) per tile, int8
#define THREADS 256           // 4 waves, 2x2; per-wave output 128x128
#define NT (K_DIM / BKB)      // 24 K-tiles

// ws layout (int8 path): W8 [N][K] i8, X8 [M][K] i8, Ro/RoInv [N] f32, Sx [M] f32
#define W8_OFF  ((size_t)0)
#define X8_OFF  ((size_t)N_DIM * K_DIM)
#define RO_OFF  (X8_OFF + (size_t)M_DIM * K_DIM)
#define ROI_OFF (RO_OFF + (size_t)N_DIM * 4)
#define SX_OFF  (ROI_OFF + (size_t)N_DIM * 4)
#define WS_NEED (SX_OFF + (size_t)M_DIM * 4)

#define WQB (N_DIM * K_DIM / 16 / 256)   // 9216 blocks, W quant

#define BAR()   asm volatile("s_barrier" ::: "memory")
#define SBAR()  __builtin_amdgcn_sched_barrier(0)

__device__ __forceinline__ void gload_lds16(const void* g, void* l) {
    // async global->LDS, 16B/lane; LDS dest = wave-uniform base + lane*16
    __builtin_amdgcn_global_load_lds(
        (const __attribute__((address_space(1))) unsigned int*)g,
        (__attribute__((address_space(3))) unsigned int*)l, 16, 0, 0);
}

// ---------------- P0a: per-output-row scale max (Ro = max_b s[o,b]) --------
__global__ __launch_bounds__(256) void romax_kernel(
    const float* __restrict__ scales, float* __restrict__ Ro,
    float* __restrict__ RoInv)
{
    int o = blockIdx.x * 256 + threadIdx.x;          // 12288 rows
    const float* p = scales + (size_t)o * NBLK;
    float mx = 1e-20f;
#pragma unroll
    for (int i = 0; i < 24; ++i) {
        f32x4 v = *(const f32x4*)(p + i * 4);
        mx = fmaxf(mx, fmaxf(fmaxf(v[0], v[1]), fmaxf(v[2], v[3])));
    }
    Ro[o] = mx;
    RoInv[o] = 1.f / mx;
}

// ---------------- P0b (fused): x row absmax + quantize, single pass ---------
__global__ __launch_bounds__(256) void xprep_kernel(
    const float* __restrict__ x, float* __restrict__ Sx,
    signed char* __restrict__ X8)
{
    const int row = blockIdx.x;                      // 4096 rows
    const int tid = threadIdx.x;
    const float* p = x + (size_t)row * K_DIM;
    f32x4 v[3];
    float mx = 1e-20f;
#pragma unroll
    for (int i = 0; i < 3; ++i) {
        v[i] = *(const f32x4*)(p + i * 1024 + tid * 4);
        mx = fmaxf(mx, fmaxf(fmaxf(fabsf(v[i][0]), fabsf(v[i][1])),
                             fmaxf(fabsf(v[i][2]), fabsf(v[i][3]))));
    }
#pragma unroll
    for (int off = 32; off; off >>= 1) mx = fmaxf(mx, __shfl_xor(mx, off));
    __shared__ float red[4];
    if ((tid & 63) == 0) red[tid >> 6] = mx;
    __syncthreads();
    mx = fmaxf(fmaxf(red[0], red[1]), fmaxf(red[2], red[3]));
    if (tid == 0) Sx[row] = mx / 127.f;
    const float f = 127.f / mx;
    signed char* xo = X8 + (size_t)row * K_DIM;
#pragma unroll
    for (int i = 0; i < 3; ++i) {
        unsigned b0 = (unsigned)__float2int_rn(v[i][0] * f) & 0xffu;
        unsigned b1 = (unsigned)__float2int_rn(v[i][1] * f) & 0xffu;
        unsigned b2 = (unsigned)__float2int_rn(v[i][2] * f) & 0xffu;
        unsigned b3 = (unsigned)__float2int_rn(v[i][3] * f) & 0xffu;
        *(unsigned*)&xo[i * 1024 + tid * 4] = b0 | (b1 << 8) | (b2 << 16) | (b3 << 24);
    }
}

// ---------------- P1: requant W -> i8 (w8 = rint(s_b*q/Ro), |w8|<=127) ------
__global__ __launch_bounds__(256) void wquant_kernel(
    const int* __restrict__ wq, const float* __restrict__ scales,
    const float* __restrict__ RoInv, signed char* __restrict__ W8)
{
    unsigned c = blockIdx.x * 256u + threadIdx.x;    // 16-elem chunk
    unsigned o = c / 192u;                           // 192 chunks per row
    unsigned j = c - o * 192u;
    float f = scales[o * NBLK + (j >> 1)] * RoInv[o];
    const int* gq = wq + (size_t)c * 16;
    i8x16 v;
#pragma unroll
    for (int i = 0; i < 4; ++i) {
        i32x4 q = *(const i32x4*)(gq + i * 4);
        v[i * 4 + 0] = (signed char)__float2int_rn((float)q[0] * f);
        v[i * 4 + 1] = (signed char)__float2int_rn((float)q[1] * f);
        v[i * 4 + 2] = (signed char)__float2int_rn((float)q[2] * f);
        v[i * 4 + 3] = (signed char)__float2int_rn((float)q[3] * f);
    }
    *(i8x16*)&W8[(size_t)c * 16] = v;
}

// ------ Pass 2: 4-wave i8 GEMM, per-wave 128x128 (64 FLOP/LDS-byte) ---------
// out[t][o] = Sx[t]*Ro[o]*(sum_k x8[t][k]*w8[o][k]) + bias[o]
// r13 rotated schedule at 4 waves (2Mx2N): LDS reads/tile 192->128 KB (+50%
// arithmetic intensity per wave), tile flips compute-bound (MFMA 2610 cyc vs
// LDS ~2260). Registers: acc 256 + frags ~192 < 450 no-spill line (m08).
// Staging: 256 threads, unit = whole 256x128B operand = 8 issues of 32 rows.
//  phA: rd AF1 (8 ds) | stB(nxt, half0, t+1) 4 iss | q00
//  phB: rd BG1 (8 ds) | stB(nxt, half1, t+1) 4 iss | q10 | BAR
//  phC: stA(cur, t+2) 8 iss | q11 | vmcnt(8) | BAR
//  phD: rd AF0',BG0' (16 ds from nxt)              | q01 (regs only)
// vmcnt(8): FIFO = [A(t+1) x8, B(t+1) x8, A(t+2) x8] -> drains 16, keeps 8.
// Swizzle both-sides (rule #21) unchanged; 16 lanes over 8 chunk-slots =
// 2-way aliasing = free (m136).
__global__ __launch_bounds__(THREADS, 1) void gemm_i8w_kernel(
    const signed char* __restrict__ A8, const signed char* __restrict__ B8,
    const float* __restrict__ Ro, const float* __restrict__ Sx,
    const float* __restrict__ bias, float* __restrict__ out)
{
    __shared__ __align__(16) signed char sA8[2][BM * BKB];   // 2 x 32 KB
    __shared__ __align__(16) signed char sB8[2][BN * BKB];   // 2 x 32 KB

    const int tid  = threadIdx.x;
    const int bm   = blockIdx.x / (N_DIM / BN);
    const int bn   = blockIdx.x % (N_DIM / BN);
    const int row0 = bm * BM;
    const int col0 = bn * BN;

    const int lane = tid & 63;
    const int wid  = tid >> 6;          // 4 waves: 2 (M) x 2 (N)
    const int wr   = (wid >> 1) * 128;  // wave row offset
    const int wc   = (wid & 1) * 128;   // wave col offset
    const int fr   = lane & 15;         // fragment row within 16
    const int kq   = lane >> 4;         // k-16B-chunk quarter 0..3

    // staging: issue j covers rows j*32 + rws (rws = tid>>3, 0..31)
    const int rws = tid >> 3;
    const int c8s = (tid & 7) ^ (rws & 7);            // pre-swizzled chunk col
    const signed char* srcA = A8 + (size_t)(row0 + rws) * K_DIM + c8s * 16;
    const signed char* srcB = B8 + (size_t)(col0 + rws) * K_DIM + c8s * 16;
    const int ldsU = (tid & ~63) * 16;                // wave-uniform byte base

    auto stA = [&](int d, int tt) {                   // full 256x128B: 8 issues
#pragma unroll
        for (int j = 0; j < 8; ++j)
            gload_lds16(srcA + (size_t)tt * BKB + (size_t)(j * 32) * K_DIM,
                        &sA8[d][j * 4096 + ldsU]);
    };
    auto stB = [&](int d, int h, int tt) {            // half: 4 issues
#pragma unroll
        for (int j = 0; j < 4; ++j)
            gload_lds16(srcB + (size_t)tt * BKB + (size_t)((h * 4 + j) * 32) * K_DIM,
                        &sB8[d][(h * 4 + j) * 4096 + ldsU]);
    };

    i32x4 acc[8][8];
#pragma unroll
    for (int m = 0; m < 8; ++m)
#pragma unroll
        for (int n = 0; n < 8; ++n) acc[m][n] = (i32x4)0;

    auto rdF = [&](const signed char* p, int rbase, i32x4 (&dst)[4][2]) {
#pragma unroll
        for (int m = 0; m < 4; ++m) {
            int row = rbase + m * 16 + fr;
#pragma unroll
            for (int ks = 0; ks < 2; ++ks) {
                int kc = ks * 4 + kq;
                dst[m][ks] = *(const i32x4*)(p + row * BKB + ((kc ^ (row & 7)) << 4));
            }
        }
    };
    // quadrant: 4m x 4n x 2ks = 32 MFMA
    auto mm = [&](i32x4 (&a)[4][2], i32x4 (&b)[4][2], int mo, int no) {
        __builtin_amdgcn_s_setprio(1);
#pragma unroll
        for (int m = 0; m < 4; ++m)
#pragma unroll
            for (int n = 0; n < 4; ++n)
#pragma unroll
                for (int ks = 0; ks < 2; ++ks)
                    acc[mo + m][no + n] = __builtin_amdgcn_mfma_i32_16x16x64_i8(
                        a[m][ks], b[n][ks], acc[mo + m][no + n], 0, 0, 0);
        __builtin_amdgcn_s_setprio(0);
    };

    // register banks (alternate per tile; static indexing, rule #20)
    i32x4 af0a[4][2], bg0a[4][2];
    i32x4 af0b[4][2], bg0b[4][2];

    // ---- prologue: A0 x8, B0 x8, A1 x8; vmcnt(8) keeps A1; read AF0,BG0 ----
    stA(0, 0);
    stB(0, 0, 0); stB(0, 1, 0);
    stA(1, 1);
    asm volatile("s_waitcnt vmcnt(8)" ::: "memory");
    BAR();
    rdF(&sA8[0][0], wr, af0a); rdF(&sB8[0][0], wc, bg0a);

    auto ktile = [&](int cur, int t,
                     i32x4 (&AF0)[4][2], i32x4 (&BG0)[4][2],
                     i32x4 (&AF0n)[4][2], i32x4 (&BG0n)[4][2]) {
        const signed char* pA  = &sA8[cur][0];
        const signed char* pB  = &sB8[cur][0];
        const signed char* pAn = &sA8[cur ^ 1][0];
        const signed char* pBn = &sB8[cur ^ 1][0];
        int t1 = t + 1; if (t1 >= NT) t1 -= NT;   // tail: dummy wrap refetch
        int t2 = t + 2; if (t2 >= NT) t2 -= NT;

        i32x4 AF1[4][2], BG1[4][2];

        // phA: q00 | read AF1 | stage B half0(t+1)
        rdF(pA, wr + 64, AF1);
        stB(cur ^ 1, 0, t1);
        SBAR();
        mm(AF0, BG0, 0, 0);

        // phB: q10 | read BG1 | stage B half1(t+1) | BAR
        rdF(pB, wc + 64, BG1);
        stB(cur ^ 1, 1, t1);
        SBAR();
        mm(AF1, BG0, 4, 0);
        BAR();

        // phC: q11 | stage A(t+2) into cur | vmcnt(8) BAR (publish nxt)
        stA(cur, t2);
        SBAR();
        mm(AF1, BG1, 4, 4);
        SBAR();
        asm volatile("s_waitcnt vmcnt(8)" ::: "memory");
        BAR();

        // phD: read next tile's AF0/BG0 from buf[nxt] | q01 under the drain
        rdF(pAn, wr, AF0n); rdF(pBn, wc, BG0n);
        SBAR();
        mm(AF0, BG1, 0, 4);
    };

    for (int it = 0; it < NT / 2; ++it) {
        ktile(0, it * 2,     af0a, bg0a, af0b, bg0b);
        ktile(1, it * 2 + 1, af0b, bg0b, af0a, bg0a);
    }

    // ---- epilogue: C/D col=lane&15, row=(lane>>4)*4+j; scale by Ro*Sx ----
    const int crow = (lane >> 4) << 2;
    const int ccol = lane & 15;
    float ro[8], bb[8];
#pragma unroll
    for (int n = 0; n < 8; ++n) {
        int col = col0 + wc + n * 16 + ccol;
        ro[n] = Ro[col];
        bb[n] = bias[col];
    }
#pragma unroll
    for (int m = 0; m < 8; ++m) {
#pragma unroll
        for (int j = 0; j < 4; ++j) {
            int row = row0 + wr + m * 16 + crow + j;
            float sx = Sx[row];
            size_t base = (size_t)row * N_DIM + col0 + wc + ccol;
#pragma unroll
            for (int n = 0; n < 8; ++n)
                out[base + n * 16] = (float)acc[m][n][j] * ro[n] * sx + bb[n];
        }
    }
}

// ---------------- Fallback: fused bf16 kernel (if ws too small) -------------
#define FBM 128
#define FBN 128
#define FBK 64
#define FTHREADS 256
__global__ __launch_bounds__(FTHREADS) void dq_gemm_fused_kernel(
    const float* __restrict__ x, const int* __restrict__ wq,
    const float* __restrict__ scales, const float* __restrict__ bias,
    float* __restrict__ out)
{
    __shared__ bf16_t fA[FBM * FBK];
    __shared__ bf16_t fB[FBN * FBK];

    const int tid  = threadIdx.x;
    const int bm   = blockIdx.x / (N_DIM / FBN);
    const int bn   = blockIdx.x % (N_DIM / FBN);
    const int row0 = bm * FBM;
    const int col0 = bn * FBN;
    const int lane = tid & 63;
    const int wid  = tid >> 6;
    const int wr   = (wid >> 1) * 64;
    const int wc   = (wid & 1) * 64;
    const int fr   = lane & 15;
    const int fk   = (lane >> 4) << 3;

    f32x4 acc[4][4];
#pragma unroll
    for (int m = 0; m < 4; ++m)
#pragma unroll
        for (int n = 0; n < 4; ++n) acc[m][n] = (f32x4)0.f;

    for (int kt = 0; kt < K_DIM / FBK; ++kt) {
        const int kb = kt * FBK;
#pragma unroll
        for (int c = 0; c < 4; ++c) {
            int i  = c * FTHREADS + tid;
            int r  = i >> 3;
            int k0 = (i & 7) << 3;
            const float* gp = x + (size_t)(row0 + r) * K_DIM + kb + k0;
            f32x4 f0 = *(const f32x4*)gp;
            f32x4 f1 = *(const f32x4*)(gp + 4);
            bf16x8 v;
            v[0] = (bf16_t)f0[0]; v[1] = (bf16_t)f0[1];
            v[2] = (bf16_t)f0[2]; v[3] = (bf16_t)f0[3];
            v[4] = (bf16_t)f1[0]; v[5] = (bf16_t)f1[1];
            v[6] = (bf16_t)f1[2]; v[7] = (bf16_t)f1[3];
            *(bf16x8*)&fA[r * FBK + (k0 ^ ((r & 7) << 3))] = v;
        }
#pragma unroll
        for (int c = 0; c < 4; ++c) {
            int i  = c * FTHREADS + tid;
            int r  = i >> 3;
            int k0 = (i & 7) << 3;
            int o  = col0 + r;
            const int* gq = wq + (size_t)o * K_DIM + kb + k0;
            i32x4 q0 = *(const i32x4*)gq;
            i32x4 q1 = *(const i32x4*)(gq + 4);
            float s = scales[o * NBLK + ((kb + k0) >> 5)];
            bf16x8 v;
            v[0] = (bf16_t)((float)q0[0] * s); v[1] = (bf16_t)((float)q0[1] * s);
            v[2] = (bf16_t)((float)q0[2] * s); v[3] = (bf16_t)((float)q0[3] * s);
            v[4] = (bf16_t)((float)q1[0] * s); v[5] = (bf16_t)((float)q1[1] * s);
            v[6] = (bf16_t)((float)q1[2] * s); v[7] = (bf16_t)((float)q1[3] * s);
            *(bf16x8*)&fB[r * FBK + (k0 ^ ((r & 7) << 3))] = v;
        }
        __syncthreads();
#pragma unroll
        for (int ks = 0; ks < 2; ++ks) {
            bf16x8 af[4], bg[4];
#pragma unroll
            for (int m = 0; m < 4; ++m) {
                int r = wr + m * 16 + fr;
                af[m] = *(const bf16x8*)&fA[r * FBK + ((ks * 32 + fk) ^ ((r & 7) << 3))];
            }
#pragma unroll
            for (int n = 0; n < 4; ++n) {
                int r = wc + n * 16 + fr;
                bg[n] = *(const bf16x8*)&fB[r * FBK + ((ks * 32 + fk) ^ ((r & 7) << 3))];
            }
#pragma unroll
            for (int m = 0; m < 4; ++m)
#pragma unroll
                for (int n = 0; n < 4; ++n)
                    acc[m][n] = __builtin_amdgcn_mfma_f32_16x16x32_bf16(
                        af[m], bg[n], acc[m][n], 0, 0, 0);
        }
        __syncthreads();
    }

    const int crow = (lane >> 4) << 2;
    const int ccol = lane & 15;
#pragma unroll
    for (int m = 0; m < 4; ++m) {
#pragma unroll
        for (int n = 0; n < 4; ++n) {
            int col = col0 + wc + n * 16 + ccol;
            float b = bias[col];
#pragma unroll
            for (int j = 0; j < 4; ++j) {
                int row = row0 + wr + m * 16 + crow + j;
                out[(size_t)row * N_DIM + col] = acc[m][n][j] + b;
            }
        }
    }
}

extern "C" void kernel_launch(void* const* d_in, const int* in_sizes, int n_in,
                              void* d_out, int out_size, void* d_ws, size_t ws_size,
                              hipStream_t stream) {
    const float* x      = (const float*)d_in[0];
    const int*   wq     = (const int*)d_in[1];
    const float* scales = (const float*)d_in[2];
    const float* bias   = (const float*)d_in[3];
    float*       out    = (float*)d_out;

    if (ws_size >= WS_NEED) {
        signed char* W8    = (signed char*)d_ws + W8_OFF;
        signed char* X8    = (signed char*)d_ws + X8_OFF;
        float*       Ro    = (float*)((char*)d_ws + RO_OFF);
        float*       RoInv = (float*)((char*)d_ws + ROI_OFF);
        float*       Sx    = (float*)((char*)d_ws + SX_OFF);

        romax_kernel<<<dim3(N_DIM / 256), dim3(256), 0, stream>>>(scales, Ro, RoInv);
        xprep_kernel<<<dim3(M_DIM), dim3(256), 0, stream>>>(x, Sx, X8);
        wquant_kernel<<<dim3(WQB), dim3(256), 0, stream>>>(wq, scales, RoInv, W8);
        gemm_i8w_kernel<<<dim3((M_DIM / BM) * (N_DIM / BN)), dim3(THREADS), 0, stream>>>(
            X8, W8, Ro, Sx, bias, out);
    } else {
        dq_gemm_fused_kernel<<<dim3((M_DIM / FBM) * (N_DIM / FBN)), dim3(FTHREADS), 0, stream>>>(
            x, wq, scales, bias, out);
    }
}

// Round 17
// 203.569 us; speedup vs baseline: 2.3608x; 2.3608x over previous
//
#include <hip/hip_runtime.h>
#include <hip/hip_bf16.h>

typedef __bf16 bf16_t;
typedef __bf16 bf16x8 __attribute__((ext_vector_type(8)));
typedef float  f32x4  __attribute__((ext_vector_type(4)));
typedef int    i32x4  __attribute__((ext_vector_type(4)));
typedef signed char i8x16 __attribute__((ext_vector_type(16)));

#define M_DIM 4096
#define N_DIM 12288
#define K_DIM 3072
#define NBLK  96      // K_DIM / 32 quant blocks per output row

#define BM 256
#define BN 256
#define BKB 128               // K-bytes (=elems) per tile, int8
#define THREADS 512
#define NT (K_DIM / BKB)      // 24 K-tiles

// ws layout (int8 path): W8 [N][K] i8, X8 [M][K] i8, Ro/RoInv [N] f32, Sx [M] f32
#define W8_OFF  ((size_t)0)
#define X8_OFF  ((size_t)N_DIM * K_DIM)
#define RO_OFF  (X8_OFF + (size_t)M_DIM * K_DIM)
#define ROI_OFF (RO_OFF + (size_t)N_DIM * 4)
#define SX_OFF  (ROI_OFF + (size_t)N_DIM * 4)
#define WS_NEED (SX_OFF + (size_t)M_DIM * 4)

#define WQB (N_DIM * K_DIM / 16 / 256)   // 9216 blocks, W quant
#define ROB (N_DIM / 256)                // 48 blocks, Ro max

#define BAR()   asm volatile("s_barrier" ::: "memory")
#define SBAR()  __builtin_amdgcn_sched_barrier(0)

__device__ __forceinline__ void gload_lds16(const void* g, void* l) {
    // async global->LDS, 16B/lane; LDS dest = wave-uniform base + lane*16
    __builtin_amdgcn_global_load_lds(
        (const __attribute__((address_space(1))) unsigned int*)g,
        (__attribute__((address_space(3))) unsigned int*)l, 16, 0, 0);
}

// ------- P0 (merged): Ro scale-max (blocks 0..47) | x absmax+quant ----------
// Independent tasks, block-range split. Ro side: one thread per output row.
// xprep side: one block per x row; values held in regs across max->quantize.
__global__ __launch_bounds__(256) void prep0_kernel(
    const float* __restrict__ scales, float* __restrict__ Ro,
    float* __restrict__ RoInv,
    const float* __restrict__ x, float* __restrict__ Sx,
    signed char* __restrict__ X8)
{
    const int b = blockIdx.x;
    if (b < ROB) {
        int o = b * 256 + threadIdx.x;               // 12288 rows
        const float* p = scales + (size_t)o * NBLK;
        float mx = 1e-20f;
#pragma unroll
        for (int i = 0; i < 24; ++i) {
            f32x4 v = *(const f32x4*)(p + i * 4);
            mx = fmaxf(mx, fmaxf(fmaxf(v[0], v[1]), fmaxf(v[2], v[3])));
        }
        Ro[o] = mx;
        RoInv[o] = 1.f / mx;
        return;
    }
    const int row = b - ROB;                         // 4096 rows
    const int tid = threadIdx.x;
    const float* p = x + (size_t)row * K_DIM;
    f32x4 v[3];
    float mx = 1e-20f;
#pragma unroll
    for (int i = 0; i < 3; ++i) {
        v[i] = *(const f32x4*)(p + i * 1024 + tid * 4);
        mx = fmaxf(mx, fmaxf(fmaxf(fabsf(v[i][0]), fabsf(v[i][1])),
                             fmaxf(fabsf(v[i][2]), fabsf(v[i][3]))));
    }
#pragma unroll
    for (int off = 32; off; off >>= 1) mx = fmaxf(mx, __shfl_xor(mx, off));
    __shared__ float red[4];
    if ((tid & 63) == 0) red[tid >> 6] = mx;
    __syncthreads();
    mx = fmaxf(fmaxf(red[0], red[1]), fmaxf(red[2], red[3]));
    if (tid == 0) Sx[row] = mx / 127.f;
    const float f = 127.f / mx;
    signed char* xo = X8 + (size_t)row * K_DIM;
#pragma unroll
    for (int i = 0; i < 3; ++i) {
        unsigned b0 = (unsigned)__float2int_rn(v[i][0] * f) & 0xffu;
        unsigned b1 = (unsigned)__float2int_rn(v[i][1] * f) & 0xffu;
        unsigned b2 = (unsigned)__float2int_rn(v[i][2] * f) & 0xffu;
        unsigned b3 = (unsigned)__float2int_rn(v[i][3] * f) & 0xffu;
        *(unsigned*)&xo[i * 1024 + tid * 4] = b0 | (b1 << 8) | (b2 << 16) | (b3 << 24);
    }
}

// ---------------- P1: requant W -> i8 (w8 = rint(s_b*q/Ro), |w8|<=127) ------
__global__ __launch_bounds__(256) void wquant_kernel(
    const int* __restrict__ wq, const float* __restrict__ scales,
    const float* __restrict__ RoInv, signed char* __restrict__ W8)
{
    unsigned c = blockIdx.x * 256u + threadIdx.x;    // 16-elem chunk
    unsigned o = c / 192u;                           // 192 chunks per row
    unsigned j = c - o * 192u;
    float f = scales[o * NBLK + (j >> 1)] * RoInv[o];
    const int* gq = wq + (size_t)c * 16;
    i8x16 v;
#pragma unroll
    for (int i = 0; i < 4; ++i) {
        i32x4 q = *(const i32x4*)(gq + i * 4);
        v[i * 4 + 0] = (signed char)__float2int_rn((float)q[0] * f);
        v[i * 4 + 1] = (signed char)__float2int_rn((float)q[1] * f);
        v[i * 4 + 2] = (signed char)__float2int_rn((float)q[2] * f);
        v[i * 4 + 3] = (signed char)__float2int_rn((float)q[3] * f);
    }
    *(i8x16*)&W8[(size_t)c * 16] = v;
}

// ---------------- Pass 2: r13/r15 rotated-read i8 GEMM (verified best) ------
// out[t][o] = Sx[t]*Ro[o]*(sum_k x8[t][k]*w8[o][k]) + bias[o]
// 152us, 44% MfmaUtil, 0 conflicts, VGPR 128. Closed levers (measured):
// smaller per-wave (r4), barrier-pairs (r9), SGB weave (r10), 32x32 MFMA
// (r11: chunk-space conflict), B-direct-to-reg (r14: latency+regs),
// per-wave 128x128 (r16: acc spill at 256 regs). Floors: HBM 40us, MFMA
// 78us, LDS 90us; residual 1.7x is the compiler barrier-drain structure
// ceiling (m97-class), passable only via hand-asm K-loops.
//  phA: rd af1 (8)  | stB(nxt,u0,t+1) | q00
//  phB: rd bg1 (4)  | stB(nxt,u1,t+1) | q10             | BAR
//  phC: stA(cur,u0+u1,t+2)            | q11 | vmcnt(4)  | BAR
//  phD: rd af0',bg0' (12) from buf[nxt]                 | q01 (regs only)
// vmcnt(4) drains A(t+1)+B(t+1), keeps A(t+2)'s 4 in flight (never 0).
// Swizzle both-sides (rule #21): linear LDS chunk (row,c16) holds global
// chunk (row, c16^(row&7)) via pre-swizzled source; reads XOR the same.
__global__ __launch_bounds__(THREADS, 2) void gemm_i8_kernel(
    const signed char* __restrict__ A8, const signed char* __restrict__ B8,
    const float* __restrict__ Ro, const float* __restrict__ Sx,
    const float* __restrict__ bias, float* __restrict__ out)
{
    __shared__ __align__(16) signed char sA8[2][BM * BKB];   // 2 x 32 KB
    __shared__ __align__(16) signed char sB8[2][BN * BKB];   // 2 x 32 KB

    const int tid  = threadIdx.x;
    const int bm   = blockIdx.x / (N_DIM / BN);
    const int bn   = blockIdx.x % (N_DIM / BN);
    const int row0 = bm * BM;
    const int col0 = bn * BN;

    const int lane = tid & 63;
    const int wid  = tid >> 6;          // 8 waves: 2 (M) x 4 (N)
    const int wr   = (wid >> 2) * 128;
    const int wc   = (wid & 3) * 64;
    const int fr   = lane & 15;         // fragment row within 16
    const int kq   = lane >> 4;         // k-16B-chunk quarter 0..3

    // staging: unit = 128 rows x 128B (16 KB) = 2 issues/thread
    const int rws = tid >> 3;                         // 0..63
    const int c8s = (tid & 7) ^ (rws & 7);            // pre-swizzled chunk col
    const signed char* srcA = A8 + (size_t)(row0 + rws) * K_DIM + c8s * 16;
    const signed char* srcB = B8 + (size_t)(col0 + rws) * K_DIM + c8s * 16;
    const int ldsU = (tid & ~63) * 16;                // wave-uniform byte base

    auto stA = [&](int d, int uh, int tt) {
        const signed char* s = srcA + (size_t)tt * BKB + (size_t)uh * 128 * K_DIM;
        gload_lds16(s,                        &sA8[d][uh * 16384 + ldsU]);
        gload_lds16(s + (size_t)64 * K_DIM,   &sA8[d][uh * 16384 + 8192 + ldsU]);
    };
    auto stB = [&](int d, int uh, int tt) {
        const signed char* s = srcB + (size_t)tt * BKB + (size_t)uh * 128 * K_DIM;
        gload_lds16(s,                        &sB8[d][uh * 16384 + ldsU]);
        gload_lds16(s + (size_t)64 * K_DIM,   &sB8[d][uh * 16384 + 8192 + ldsU]);
    };

    i32x4 acc[8][4];
#pragma unroll
    for (int m = 0; m < 8; ++m)
#pragma unroll
        for (int n = 0; n < 4; ++n) acc[m][n] = (i32x4)0;

    auto rdA = [&](const signed char* pA, int rbase, i32x4 (&dst)[4][2]) {
#pragma unroll
        for (int m = 0; m < 4; ++m) {
            int row = rbase + m * 16 + fr;
#pragma unroll
            for (int ks = 0; ks < 2; ++ks) {
                int kc = ks * 4 + kq;
                dst[m][ks] = *(const i32x4*)(pA + row * BKB + ((kc ^ (row & 7)) << 4));
            }
        }
    };
    auto rdB = [&](const signed char* pB, int rbase, i32x4 (&dst)[2][2]) {
#pragma unroll
        for (int n = 0; n < 2; ++n) {
            int row = rbase + n * 16 + fr;
#pragma unroll
            for (int ks = 0; ks < 2; ++ks) {
                int kc = ks * 4 + kq;
                dst[n][ks] = *(const i32x4*)(pB + row * BKB + ((kc ^ (row & 7)) << 4));
            }
        }
    };
    auto mm = [&](i32x4 (&a)[4][2], i32x4 (&b)[2][2], int mo, int no) {
        __builtin_amdgcn_s_setprio(1);
#pragma unroll
        for (int m = 0; m < 4; ++m)
#pragma unroll
            for (int n = 0; n < 2; ++n)
#pragma unroll
                for (int ks = 0; ks < 2; ++ks)
                    acc[mo + m][no + n] = __builtin_amdgcn_mfma_i32_16x16x64_i8(
                        a[m][ks], b[n][ks], acc[mo + m][no + n], 0, 0, 0);
        __builtin_amdgcn_s_setprio(0);
    };

    // register banks (alternate per tile; static indexing, rule #20)
    i32x4 af0a[4][2], af1a[4][2], bg0a[2][2], bg1a[2][2];
    i32x4 af0b[4][2], af1b[4][2], bg0b[2][2], bg1b[2][2];

    // ---- prologue: tile0 all units + tile1 A units; drain tile0; read 12 ----
    stA(0, 0, 0); stA(0, 1, 0); stB(0, 0, 0); stB(0, 1, 0);
    stA(1, 0, 1); stA(1, 1, 1);
    asm volatile("s_waitcnt vmcnt(4)" ::: "memory");
    BAR();
    rdA(&sA8[0][0], wr, af0a); rdB(&sB8[0][0], wc, bg0a);

    auto ktile = [&](int cur, int t,
                     i32x4 (&AF0)[4][2], i32x4 (&AF1)[4][2],
                     i32x4 (&BG0)[2][2], i32x4 (&BG1)[2][2],
                     i32x4 (&AF0n)[4][2], i32x4 (&BG0n)[2][2]) {
        const signed char* pA  = &sA8[cur][0];
        const signed char* pB  = &sB8[cur][0];
        const signed char* pAn = &sA8[cur ^ 1][0];
        const signed char* pBn = &sB8[cur ^ 1][0];
        int t1 = t + 1; if (t1 >= NT) t1 -= NT;   // tail: dummy wrap refetch
        int t2 = t + 2; if (t2 >= NT) t2 -= NT;

        // phA: q00 | read af1 | stage B u0
        rdA(pA, wr + 64, AF1);
        stB(cur ^ 1, 0, t1);
        SBAR();
        mm(AF0, BG0, 0, 0);

        // phB: q10 | read bg1 | stage B u1 | BAR
        rdB(pB, wc + 32, BG1);
        stB(cur ^ 1, 1, t1);
        SBAR();
        mm(AF1, BG0, 4, 0);
        BAR();

        // phC: q11 | stage A u0+u1 (t+2 into cur) | vmcnt(4) BAR
        stA(cur, 0, t2);
        stA(cur, 1, t2);
        SBAR();
        mm(AF1, BG1, 4, 2);
        SBAR();
        asm volatile("s_waitcnt vmcnt(4)" ::: "memory");
        BAR();

        // phD: read next tile's af0/bg0 from buf[nxt] | q01 under the drain
        rdA(pAn, wr, AF0n); rdB(pBn, wc, BG0n);
        SBAR();
        mm(AF0, BG1, 0, 2);
    };

    for (int it = 0; it < NT / 2; ++it) {
        ktile(0, it * 2,     af0a, af1a, bg0a, bg1a, af0b, bg0b);
        ktile(1, it * 2 + 1, af0b, af1b, bg0b, bg1b, af0a, bg0a);
    }

    // ---- epilogue: C/D col=lane&15, row=(lane>>4)*4+j; scale by Ro*Sx ----
    const int crow = (lane >> 4) << 2;
    const int ccol = lane & 15;
    float ro[4], bb[4];
#pragma unroll
    for (int n = 0; n < 4; ++n) {
        int col = col0 + wc + n * 16 + ccol;
        ro[n] = Ro[col];
        bb[n] = bias[col];
    }
#pragma unroll
    for (int m = 0; m < 8; ++m) {
#pragma unroll
        for (int j = 0; j < 4; ++j) {
            int row = row0 + wr + m * 16 + crow + j;
            float sx = Sx[row];
            size_t base = (size_t)row * N_DIM + col0 + wc + ccol;
#pragma unroll
            for (int n = 0; n < 4; ++n)
                out[base + n * 16] = (float)acc[m][n][j] * ro[n] * sx + bb[n];
        }
    }
}

// ---------------- Fallback: fused bf16 kernel (if ws too small) -------------
#define FBM 128
#define FBN 128
#define FBK 64
#define FTHREADS 256
__global__ __launch_bounds__(FTHREADS) void dq_gemm_fused_kernel(
    const float* __restrict__ x, const int* __restrict__ wq,
    const float* __restrict__ scales, const float* __restrict__ bias,
    float* __restrict__ out)
{
    __shared__ bf16_t fA[FBM * FBK];
    __shared__ bf16_t fB[FBN * FBK];

    const int tid  = threadIdx.x;
    const int bm   = blockIdx.x / (N_DIM / FBN);
    const int bn   = blockIdx.x % (N_DIM / FBN);
    const int row0 = bm * FBM;
    const int col0 = bn * FBN;
    const int lane = tid & 63;
    const int wid  = tid >> 6;
    const int wr   = (wid >> 1) * 64;
    const int wc   = (wid & 1) * 64;
    const int fr   = lane & 15;
    const int fk   = (lane >> 4) << 3;

    f32x4 acc[4][4];
#pragma unroll
    for (int m = 0; m < 4; ++m)
#pragma unroll
        for (int n = 0; n < 4; ++n) acc[m][n] = (f32x4)0.f;

    for (int kt = 0; kt < K_DIM / FBK; ++kt) {
        const int kb = kt * FBK;
#pragma unroll
        for (int c = 0; c < 4; ++c) {
            int i  = c * FTHREADS + tid;
            int r  = i >> 3;
            int k0 = (i & 7) << 3;
            const float* gp = x + (size_t)(row0 + r) * K_DIM + kb + k0;
            f32x4 f0 = *(const f32x4*)gp;
            f32x4 f1 = *(const f32x4*)(gp + 4);
            bf16x8 v;
            v[0] = (bf16_t)f0[0]; v[1] = (bf16_t)f0[1];
            v[2] = (bf16_t)f0[2]; v[3] = (bf16_t)f0[3];
            v[4] = (bf16_t)f1[0]; v[5] = (bf16_t)f1[1];
            v[6] = (bf16_t)f1[2]; v[7] = (bf16_t)f1[3];
            *(bf16x8*)&fA[r * FBK + (k0 ^ ((r & 7) << 3))] = v;
        }
#pragma unroll
        for (int c = 0; c < 4; ++c) {
            int i  = c * FTHREADS + tid;
            int r  = i >> 3;
            int k0 = (i & 7) << 3;
            int o  = col0 + r;
            const int* gq = wq + (size_t)o * K_DIM + kb + k0;
            i32x4 q0 = *(const i32x4*)gq;
            i32x4 q1 = *(const i32x4*)(gq + 4);
            float s = scales[o * NBLK + ((kb + k0) >> 5)];
            bf16x8 v;
            v[0] = (bf16_t)((float)q0[0] * s); v[1] = (bf16_t)((float)q0[1] * s);
            v[2] = (bf16_t)((float)q0[2] * s); v[3] = (bf16_t)((float)q0[3] * s);
            v[4] = (bf16_t)((float)q1[0] * s); v[5] = (bf16_t)((float)q1[1] * s);
            v[6] = (bf16_t)((float)q1[2] * s); v[7] = (bf16_t)((float)q1[3] * s);
            *(bf16x8*)&fB[r * FBK + (k0 ^ ((r & 7) << 3))] = v;
        }
        __syncthreads();
#pragma unroll
        for (int ks = 0; ks < 2; ++ks) {
            bf16x8 af[4], bg[4];
#pragma unroll
            for (int m = 0; m < 4; ++m) {
                int r = wr + m * 16 + fr;
                af[m] = *(const bf16x8*)&fA[r * FBK + ((ks * 32 + fk) ^ ((r & 7) << 3))];
            }
#pragma unroll
            for (int n = 0; n < 4; ++n) {
                int r = wc + n * 16 + fr;
                bg[n] = *(const bf16x8*)&fB[r * FBK + ((ks * 32 + fk) ^ ((r & 7) << 3))];
            }
#pragma unroll
            for (int m = 0; m < 4; ++m)
#pragma unroll
                for (int n = 0; n < 4; ++n)
                    acc[m][n] = __builtin_amdgcn_mfma_f32_16x16x32_bf16(
                        af[m], bg[n], acc[m][n], 0, 0, 0);
        }
        __syncthreads();
    }

    const int crow = (lane >> 4) << 2;
    const int ccol = lane & 15;
#pragma unroll
    for (int m = 0; m < 4; ++m) {
#pragma unroll
        for (int n = 0; n < 4; ++n) {
            int col = col0 + wc + n * 16 + ccol;
            float b = bias[col];
#pragma unroll
            for (int j = 0; j < 4; ++j) {
                int row = row0 + wr + m * 16 + crow + j;
                out[(size_t)row * N_DIM + col] = acc[m][n][j] + b;
            }
        }
    }
}

extern "C" void kernel_launch(void* const* d_in, const int* in_sizes, int n_in,
                              void* d_out, int out_size, void* d_ws, size_t ws_size,
                              hipStream_t stream) {
    const float* x      = (const float*)d_in[0];
    const int*   wq     = (const int*)d_in[1];
    const float* scales = (const float*)d_in[2];
    const float* bias   = (const float*)d_in[3];
    float*       out    = (float*)d_out;

    if (ws_size >= WS_NEED) {
        signed char* W8    = (signed char*)d_ws + W8_OFF;
        signed char* X8    = (signed char*)d_ws + X8_OFF;
        float*       Ro    = (float*)((char*)d_ws + RO_OFF);
        float*       RoInv = (float*)((char*)d_ws + ROI_OFF);
        float*       Sx    = (float*)((char*)d_ws + SX_OFF);

        prep0_kernel<<<dim3(ROB + M_DIM), dim3(256), 0, stream>>>(
            scales, Ro, RoInv, x, Sx, X8);
        wquant_kernel<<<dim3(WQB), dim3(256), 0, stream>>>(wq, scales, RoInv, W8);
        gemm_i8_kernel<<<dim3((M_DIM / BM) * (N_DIM / BN)), dim3(THREADS), 0, stream>>>(
            X8, W8, Ro, Sx, bias, out);
    } else {
        dq_gemm_fused_kernel<<<dim3((M_DIM / FBM) * (N_DIM / FBN)), dim3(FTHREADS), 0, stream>>>(
            x, wq, scales, bias, out);
    }
}